// Round 5
// baseline (231.385 us; speedup 1.0000x reference)
//
#include <hip/hip_runtime.h>

// Problem: B=32, C=3, H=512, W=512 -> NIMG = 96 flat images
// R5 structure: grid 2048 (= 256 CU x 8 resident blocks, ONE full round, no
//   backfill tail). Each block processes 3 half-tiles (4x16 pooled each);
//   6144 half-tiles = 96 img x 64 (16 row-strips x 4 col-strips).
// Per half-tile:
//   phase 0: Haar DWT -> cA 22x70 tile in LDS (zero-pad OOB); interior 16x64
//            cH/cV written straight to d_out high region.
//   phase a/b (x4 ic-chunks): conv1(1->16)+relu+pool2 -> LDS, conv2(16->8) accum.
//   epilogue: relu+pool2 (h2 exchange via LDS), conv3(8->4,1x1) -> d_out low.
// R1: conv1/conv2 use v_pk_fma_f32 (packed fp32) over oc pairs.
// R3: SIMD-balanced task loops (equal tasks per wave); conv2 weights hoisted.
// R5: conv2 ocg = wave id (2 oc per thread, acc2[2][2]); conv3 one output per
//   thread, wave-coalesced stores. Numerics bit-identical.

typedef float v2f __attribute__((ext_vector_type(2)));

// acc(pair over oc) += w(pair over oc, SGPR) * broadcast(data.word0)
#define PK_FMA_W0(acc, w, d) \
    asm("v_pk_fma_f32 %0, %1, %2, %0 op_sel:[0,0,0] op_sel_hi:[1,0,1]" \
        : "+v"(acc) : "s"(w), "v"(d))
// acc += w * broadcast(data.word1)
#define PK_FMA_W1(acc, w, d) \
    asm("v_pk_fma_f32 %0, %1, %2, %0 op_sel:[0,1,0] op_sel_hi:[1,1,1]" \
        : "+v"(acc) : "s"(w), "v"(d))
// dst = w * broadcast(data.word0)   (accumulator init without v_mov zeroing)
#define PK_MUL_W0(dst, w, d) \
    asm("v_pk_mul_f32 %0, %1, %2 op_sel:[0,0] op_sel_hi:[1,0]" \
        : "=v"(dst) : "s"(w), "v"(d))
#define PK_MUL_W1(dst, w, d) \
    asm("v_pk_mul_f32 %0, %1, %2 op_sel:[0,1] op_sel_hi:[1,1]" \
        : "=v"(dst) : "s"(w), "v"(d))

__global__ __launch_bounds__(256, 8) void fused_all_kernel(
    const float* __restrict__ x,
    const float* __restrict__ w1, const float* __restrict__ b1,
    const float* __restrict__ w2, const float* __restrict__ b2,
    const float* __restrict__ w3, const float* __restrict__ b3,
    float* __restrict__ outLow, float* __restrict__ outHigh)
{
    __shared__ __align__(16) float ca[22 * 70];      // cA tile, rows stride 70
    __shared__ __align__(16) float h1s[4 * 10 * 34]; // conv1 chunk (reused for h2 xchg)

    int wvi = threadIdx.x >> 6;                // wave index 0..3
    int lni = threadIdx.x & 63;                // lane

    // conv2/conv3 thread mapping (tile-invariant):
    // pos = tid&63 over 4x16 pooled positions; ocg = wave id -> oc pair.
    int pos = threadIdx.x & 63;
    int ocg = __builtin_amdgcn_readfirstlane(wvi);
    int ly = pos >> 4, lx = pos & 15;

    #pragma unroll 1
    for (int j3 = 0; j3 < 3; ++j3) {
        int tIdx = blockIdx.x * 3 + j3;        // 0..6143
        int img  = tIdx >> 6;
        int s    = tIdx & 63;
        int rs = s >> 2, cs = s & 3;           // row-strip 0..15, col-strip 0..3
        int hy0 = rs * 8 - 1, hx0 = cs * 32 - 1;  // h1 tile origin (10x34 incl halo)
        int cy0 = rs * 16 - 3, cx0 = cs * 64 - 3; // cA tile origin (22x70)

        const float* xi = x + img * 262144;    // 512*512 image
        float* hb = outHigh + img * 131072;

        // ---- Phase 0a: interior 16x64 cA (coalesced), cH/cV -> global ----
        {
            int i = threadIdx.x;
            int row = i >> 4, cg = i & 15;
            int gy = rs * 16 + row;            // cA row (always in-bounds)
            int gx = cs * 64 + cg * 4;         // cA col, float4-aligned
            const float* r0 = xi + (2 * gy) * 512 + 2 * gx;
            const float* r1 = r0 + 512;
            float4 t0 = *(const float4*)(r0);
            float4 t1 = *(const float4*)(r0 + 4);
            float4 u0 = *(const float4*)(r1);
            float4 u1 = *(const float4*)(r1 + 4);
            float4 vA, vH, vV;
            vA.x = (t0.x + t0.y + u0.x + u0.y) * 0.5f;
            vH.x = (t0.x + t0.y - u0.x - u0.y) * 0.5f;
            vV.x = (t0.x - t0.y + u0.x - u0.y) * 0.5f;
            vA.y = (t0.z + t0.w + u0.z + u0.w) * 0.5f;
            vH.y = (t0.z + t0.w - u0.z - u0.w) * 0.5f;
            vV.y = (t0.z - t0.w + u0.z - u0.w) * 0.5f;
            vA.z = (t1.x + t1.y + u1.x + u1.y) * 0.5f;
            vH.z = (t1.x + t1.y - u1.x - u1.y) * 0.5f;
            vV.z = (t1.x - t1.y + u1.x - u1.y) * 0.5f;
            vA.w = (t1.z + t1.w + u1.z + u1.w) * 0.5f;
            vH.w = (t1.z + t1.w - u1.z - u1.w) * 0.5f;
            vV.w = (t1.z - t1.w + u1.z - u1.w) * 0.5f;
            int po = (gy << 8) + gx;
            *(float4*)(hb + po) = vH;
            *(float4*)(hb + 65536 + po) = vV;
            float* cp = ca + (row + 3) * 70 + cg * 4 + 3;   // odd offset: scalar stores
            cp[0] = vA.x; cp[1] = vA.y; cp[2] = vA.z; cp[3] = vA.w;
        }

        // ---- Phase 0b: 3-wide halo ring of cA (516 points), vA only ----
        // Ring = rows {0,1,2} + {19,20,21} (full width 70) + rows 3..18 with
        // cols {0,1,2,67,68,69}.  129 tasks per wave (SIMD-balanced).
        #pragma unroll
        for (int j = 0; j < 3; ++j) {
            if (j < 2 || lni < 1) {
                int i = wvi * 129 + j * 64 + lni;
                int r, c;
                if (i < 210)      { r = i / 70;              c = i - r * 70; }
                else if (i < 420) { int jj = i - 210; r = 19 + jj / 70; c = jj - (jj / 70) * 70; }
                else              { int jj = i - 420; r = 3 + jj / 6; int k6 = jj - (jj / 6) * 6;
                                    c = (k6 < 3) ? k6 : (64 + k6); }   // {0,1,2,67,68,69}
                int gy = cy0 + r, gx = cx0 + c;
                float v = 0.f;
                if ((unsigned)gy < 256u && (unsigned)gx < 256u) {
                    const float* p0 = xi + (2 * gy) * 512 + 2 * gx;
                    float2 a = *(const float2*)(p0);
                    float2 b = *(const float2*)(p0 + 512);
                    v = (a.x + a.y + b.x + b.y) * 0.5f;
                }
                ca[r * 70 + c] = v;
            }
        }

        // conv2 accumulators: 1 oc-pair for this wave x 2x2 pre-pool window
        v2f acc2[2][2];
        #pragma unroll
        for (int r = 0; r < 2; ++r)
            #pragma unroll
            for (int c = 0; c < 2; ++c) acc2[r][c] = (v2f){0.f, 0.f};

        __syncthreads();   // ca ready (also orders prev tile's h2-exchange reads
                           // before this tile's h1s writes)

        #pragma unroll 1
        for (int cc = 0; cc < 4; ++cc) {
            // conv1 weight pairs over oc for this 4-oc chunk (uniform -> SGPR pairs)
            v2f wp1[2][9];
            #pragma unroll
            for (int o2 = 0; o2 < 2; ++o2)
                #pragma unroll
                for (int k = 0; k < 9; ++k)
                    wp1[o2][k] = (v2f){ w1[(cc * 4 + o2 * 2    ) * 9 + k],
                                        w1[(cc * 4 + o2 * 2 + 1) * 9 + k] };
            if (cc) __syncthreads();   // prev chunk's conv2 reads before overwrite

            // Phase a: h1 chunk = pool2(relu(conv1)), 4 oc, 10x34 (incl conv2 halo)
            // 340 tasks, 85 per wave (SIMD-balanced: 1 full pass + 21 lanes)
            #pragma unroll 1
            for (int j = 0; j < 2; ++j) {
                if (j < 1 || lni < 21) {
                    int i = wvi * 85 + j * 64 + lni;
                    int hy = i / 34, hx = i - hy * 34;
                    const float* pb = ca + (2 * hy) * 70 + 2 * hx;
                    v2f pr[4][2];
                    #pragma unroll
                    for (int r = 0; r < 4; ++r) {
                        pr[r][0] = *(const v2f*)(pb + r * 70);
                        pr[r][1] = *(const v2f*)(pb + r * 70 + 2);
                    }
                    bool oob = ((unsigned)(hy0 + hy) >= 128u) | ((unsigned)(hx0 + hx) >= 128u);
                    v2f am[2][4];   // [ocpair][pos: p00 p01 p10 p11]
                    #pragma unroll
                    for (int ky = 0; ky < 3; ++ky)
                    #pragma unroll
                    for (int kx = 0; kx < 3; ++kx) {
                        #pragma unroll
                        for (int o2 = 0; o2 < 2; ++o2)
                        #pragma unroll
                        for (int dy = 0; dy < 2; ++dy)
                        #pragma unroll
                        for (int dx = 0; dx < 2; ++dx) {
                            v2f d = pr[ky + dy][(kx + dx) >> 1];
                            if (ky == 0 && kx == 0) {
                                if (((kx + dx) & 1) == 0) PK_MUL_W0(am[o2][dy * 2 + dx], wp1[o2][0], d);
                                else                      PK_MUL_W1(am[o2][dy * 2 + dx], wp1[o2][0], d);
                            } else {
                                if (((kx + dx) & 1) == 0) PK_FMA_W0(am[o2][dy * 2 + dx], wp1[o2][ky * 3 + kx], d);
                                else                      PK_FMA_W1(am[o2][dy * 2 + dx], wp1[o2][ky * 3 + kx], d);
                            }
                        }
                    }
                    #pragma unroll
                    for (int o2 = 0; o2 < 2; ++o2) {
                        float mx = fmaxf(fmaxf(am[o2][0].x, am[o2][1].x),
                                         fmaxf(am[o2][2].x, am[o2][3].x));
                        float my = fmaxf(fmaxf(am[o2][0].y, am[o2][1].y),
                                         fmaxf(am[o2][2].y, am[o2][3].y));
                        mx = fmaxf(mx + b1[cc * 4 + o2 * 2    ], 0.f);
                        my = fmaxf(my + b1[cc * 4 + o2 * 2 + 1], 0.f);
                        h1s[((o2 * 2    ) * 10 + hy) * 34 + hx] = oob ? 0.f : mx;
                        h1s[((o2 * 2 + 1) * 10 + hy) * 34 + hx] = oob ? 0.f : my;
                    }
                }
            }
            __syncthreads();

            // Phase b: conv2 accumulate over these 4 input channels (2 oc per wave)
            #pragma unroll
            for (int icl = 0; icl < 4; ++icl) {
                int ic = cc * 4 + icl;
                // weight pair hoisted ahead of LDS reads (s_load overlaps ds_read)
                v2f wl[9];
                {
                    int oc0 = ocg * 2;
                    #pragma unroll
                    for (int k = 0; k < 9; ++k)
                        wl[k] = (v2f){ w2[((oc0    ) * 16 + ic) * 9 + k],
                                       w2[((oc0 + 1) * 16 + ic) * 9 + k] };
                }
                const float* base = h1s + (icl * 10 + ly * 2) * 34 + lx * 2;
                v2f wr[4][2];
                #pragma unroll
                for (int r = 0; r < 4; ++r) {
                    wr[r][0] = *(const v2f*)(base + r * 34);
                    wr[r][1] = *(const v2f*)(base + r * 34 + 2);
                }
                #pragma unroll
                for (int ky = 0; ky < 3; ++ky)
                #pragma unroll
                for (int kx = 0; kx < 3; ++kx) {
                    #pragma unroll
                    for (int r = 0; r < 2; ++r)
                    #pragma unroll
                    for (int c = 0; c < 2; ++c) {
                        v2f d = wr[r + ky][(c + kx) >> 1];
                        if (((c + kx) & 1) == 0) PK_FMA_W0(acc2[r][c], wl[ky * 3 + kx], d);
                        else                     PK_FMA_W1(acc2[r][c], wl[ky * 3 + kx], d);
                    }
                }
            }
        }

        // Epilogue: bias+relu+pool2 of conv2 (2 oc per thread), exchange via LDS,
        // then conv3 (1x1, 8->4) -> low (one output per thread, coalesced)
        float h2a, h2b;
        {
            float mx = fmaxf(fmaxf(acc2[0][0].x, acc2[0][1].x),
                             fmaxf(acc2[1][0].x, acc2[1][1].x));
            float my = fmaxf(fmaxf(acc2[0][0].y, acc2[0][1].y),
                             fmaxf(acc2[1][0].y, acc2[1][1].y));
            h2a = fmaxf(mx + b2[ocg * 2    ], 0.f);
            h2b = fmaxf(my + b2[ocg * 2 + 1], 0.f);
        }
        __syncthreads();                 // conv2 done reading h1s; reuse for h2
        float* hx2 = h1s;                // [64 pos][9] stride 9 -> conflict-free
        hx2[pos * 9 + ocg * 2    ] = h2a;
        hx2[pos * 9 + ocg * 2 + 1] = h2b;
        __syncthreads();

        float hv[8];
        #pragma unroll
        for (int ic = 0; ic < 8; ++ic) hv[ic] = hx2[pos * 9 + ic];
        float* dst = outLow + img * 16384;
        int posg = (rs * 4 + ly) * 64 + cs * 16 + lx;
        int oc3 = ocg;                   // one conv3 output per thread
        float sacc = b3[oc3];
        #pragma unroll
        for (int ic = 0; ic < 8; ++ic) sacc += w3[oc3 * 8 + ic] * hv[ic];
        dst[oc3 * 4096 + posg] = sacc;
    }
}

extern "C" void kernel_launch(void* const* d_in, const int* in_sizes, int n_in,
                              void* d_out, int out_size, void* d_ws, size_t ws_size,
                              hipStream_t stream) {
    const float* x  = (const float*)d_in[0];
    const float* w1 = (const float*)d_in[1];
    const float* b1 = (const float*)d_in[2];
    const float* w2 = (const float*)d_in[3];
    const float* b2 = (const float*)d_in[4];
    const float* w3 = (const float*)d_in[5];
    const float* b3 = (const float*)d_in[6];
    float* out     = (float*)d_out;
    float* outLow  = out;                 // 1,572,864 floats
    float* outHigh = out + 1572864;       // 12,582,912 floats

    fused_all_kernel<<<2048, 256, 0, stream>>>(x, w1, b1, w2, b2, w3, b3,
                                               outLow, outHigh);
}

// Round 6
// 226.762 us; speedup vs baseline: 1.0204x; 1.0204x over previous
//
#include <hip/hip_runtime.h>

// Problem: B=32, C=3, H=512, W=512 -> NIMG = 96 flat images
// R6 structure: 8x16-pooled tiles (R2 geometry, best per-output cost), but
//   grid 1536 = 256 CU x 6 blocks, each block does 2 tiles sequentially.
//   3072 tiles = 1536 x 2 -> ONE fully-resident round, zero backfill tail.
//   __launch_bounds__(256,6) -> VGPR cap 84 (undoes R4's VGPR-32 penalty).
// Per tile:
//   phase 0: Haar DWT -> cA 38x70 tile in LDS (zero-pad OOB); interior 32x64
//            cH/cV written straight to d_out high region.
//   phase a/b (x4 ic-chunks): conv1(1->16)+relu+pool2 -> LDS, conv2(16->8) accum.
//   epilogue: relu+pool2 (h2 exchange via LDS), conv3(8->4,1x1) -> d_out low.
// R1: conv1/conv2 use v_pk_fma_f32 (packed fp32) over oc pairs.
// R3: SIMD-balanced task loops; conv2 weight pairs hoisted ahead of ds_reads.
// Numerics bit-identical to R2/R4.

typedef float v2f __attribute__((ext_vector_type(2)));

// acc(pair over oc) += w(pair over oc, SGPR) * broadcast(data.word0)
#define PK_FMA_W0(acc, w, d) \
    asm("v_pk_fma_f32 %0, %1, %2, %0 op_sel:[0,0,0] op_sel_hi:[1,0,1]" \
        : "+v"(acc) : "s"(w), "v"(d))
// acc += w * broadcast(data.word1)
#define PK_FMA_W1(acc, w, d) \
    asm("v_pk_fma_f32 %0, %1, %2, %0 op_sel:[0,1,0] op_sel_hi:[1,1,1]" \
        : "+v"(acc) : "s"(w), "v"(d))
// dst = w * broadcast(data.word0)   (accumulator init without v_mov zeroing)
#define PK_MUL_W0(dst, w, d) \
    asm("v_pk_mul_f32 %0, %1, %2 op_sel:[0,0] op_sel_hi:[1,0]" \
        : "=v"(dst) : "s"(w), "v"(d))
#define PK_MUL_W1(dst, w, d) \
    asm("v_pk_mul_f32 %0, %1, %2 op_sel:[0,1] op_sel_hi:[1,1]" \
        : "=v"(dst) : "s"(w), "v"(d))

__global__ __launch_bounds__(256, 6) void fused_all_kernel(
    const float* __restrict__ x,
    const float* __restrict__ w1, const float* __restrict__ b1,
    const float* __restrict__ w2, const float* __restrict__ b2,
    const float* __restrict__ w3, const float* __restrict__ b3,
    float* __restrict__ outLow, float* __restrict__ outHigh)
{
    __shared__ __align__(16) float ca[38 * 70];      // cA tile, rows stride 70
    __shared__ __align__(16) float h1s[4 * 18 * 34]; // conv1 chunk (reused for h2 xchg)

    int wvi = threadIdx.x >> 6;                // wave index 0..3
    int lni = threadIdx.x & 63;                // lane

    // conv2 thread mapping (tile-invariant): pos = tid&127 over 8x16 pooled
    // positions, ocg = tid>>7 picks oc {4*ocg .. 4*ocg+3}. Wave-uniform.
    int pos = threadIdx.x & 127;
    int ocg = __builtin_amdgcn_readfirstlane(threadIdx.x >> 7);
    int ly = pos >> 4, lx = pos & 15;

    #pragma unroll 1
    for (int j2 = 0; j2 < 2; ++j2) {
        int tIdx = blockIdx.x * 2 + j2;        // 0..3071
        int img  = tIdx >> 5;
        int t    = tIdx & 31;
        int tyy = t >> 2, txx = t & 3;         // 8x4 tiles: 8 pooled rows x 16 cols
        int hy0 = tyy * 16 - 1, hx0 = txx * 32 - 1; // h1 tile origin (18x34 incl halo)
        int cy0 = tyy * 32 - 3, cx0 = txx * 64 - 3; // cA tile origin (38x70)

        const float* xi = x + img * 262144;    // 512*512 image
        float* hb = outHigh + img * 131072;

        // ---- Phase 0a: interior 32x64 cA (coalesced), cH/cV -> global ----
        #pragma unroll
        for (int k = 0; k < 2; ++k) {
            int i = threadIdx.x + k * 256;
            int row = i >> 4, cg = i & 15;
            int gy = tyy * 32 + row;           // cA row (always in-bounds)
            int gx = txx * 64 + cg * 4;        // cA col, float4-aligned
            const float* r0 = xi + (2 * gy) * 512 + 2 * gx;
            const float* r1 = r0 + 512;
            float4 t0 = *(const float4*)(r0);
            float4 t1 = *(const float4*)(r0 + 4);
            float4 u0 = *(const float4*)(r1);
            float4 u1 = *(const float4*)(r1 + 4);
            float4 vA, vH, vV;
            vA.x = (t0.x + t0.y + u0.x + u0.y) * 0.5f;
            vH.x = (t0.x + t0.y - u0.x - u0.y) * 0.5f;
            vV.x = (t0.x - t0.y + u0.x - u0.y) * 0.5f;
            vA.y = (t0.z + t0.w + u0.z + u0.w) * 0.5f;
            vH.y = (t0.z + t0.w - u0.z - u0.w) * 0.5f;
            vV.y = (t0.z - t0.w + u0.z - u0.w) * 0.5f;
            vA.z = (t1.x + t1.y + u1.x + u1.y) * 0.5f;
            vH.z = (t1.x + t1.y - u1.x - u1.y) * 0.5f;
            vV.z = (t1.x - t1.y + u1.x - u1.y) * 0.5f;
            vA.w = (t1.z + t1.w + u1.z + u1.w) * 0.5f;
            vH.w = (t1.z + t1.w - u1.z - u1.w) * 0.5f;
            vV.w = (t1.z - t1.w + u1.z - u1.w) * 0.5f;
            int po = (gy << 8) + gx;
            *(float4*)(hb + po) = vH;
            *(float4*)(hb + 65536 + po) = vV;
            float* cp = ca + (row + 3) * 70 + cg * 4 + 3;   // odd offset: scalar stores
            cp[0] = vA.x; cp[1] = vA.y; cp[2] = vA.z; cp[3] = vA.w;
        }

        // ---- Phase 0b: 3-wide halo ring of cA (612 points), vA only ----
        // Ring = rows {0,1,2} + {35,36,37} (full width 70) + rows 3..34 with
        // cols {0,1,2,67,68,69}.  153 tasks per wave (SIMD-balanced).
        #pragma unroll
        for (int j = 0; j < 3; ++j) {
            if (j < 2 || lni < 25) {
                int i = wvi * 153 + j * 64 + lni;
                int r, c;
                if (i < 210)      { r = i / 70;              c = i - r * 70; }
                else if (i < 420) { int jj = i - 210; r = 35 + jj / 70; c = jj - (jj / 70) * 70; }
                else              { int jj = i - 420; r = 3 + jj / 6; int k6 = jj - (jj / 6) * 6;
                                    c = (k6 < 3) ? k6 : (64 + k6); }   // {0,1,2,67,68,69}
                int gy = cy0 + r, gx = cx0 + c;
                float v = 0.f;
                if ((unsigned)gy < 256u && (unsigned)gx < 256u) {
                    const float* p0 = xi + (2 * gy) * 512 + 2 * gx;
                    float2 a = *(const float2*)(p0);
                    float2 b = *(const float2*)(p0 + 512);
                    v = (a.x + a.y + b.x + b.y) * 0.5f;
                }
                ca[r * 70 + c] = v;
            }
        }

        // conv2 accumulators: 2 oc-pairs for this group x 2x2 pre-pool window
        v2f acc2[2][2][2];
        #pragma unroll
        for (int o2 = 0; o2 < 2; ++o2)
            #pragma unroll
            for (int r = 0; r < 2; ++r)
                #pragma unroll
                for (int c = 0; c < 2; ++c) acc2[o2][r][c] = (v2f){0.f, 0.f};

        __syncthreads();   // ca ready (also orders prev tile's h2-exchange reads
                           // before this tile's h1s writes)

        #pragma unroll 1
        for (int cc = 0; cc < 4; ++cc) {
            // conv1 weight pairs over oc for this 4-oc chunk (uniform -> SGPR pairs)
            v2f wp1[2][9];
            #pragma unroll
            for (int o2 = 0; o2 < 2; ++o2)
                #pragma unroll
                for (int k = 0; k < 9; ++k)
                    wp1[o2][k] = (v2f){ w1[(cc * 4 + o2 * 2    ) * 9 + k],
                                        w1[(cc * 4 + o2 * 2 + 1) * 9 + k] };
            if (cc) __syncthreads();   // prev chunk's conv2 reads before overwrite

            // Phase a: h1 chunk = pool2(relu(conv1)), 4 oc, 18x34 (incl conv2 halo)
            // 612 tasks, 153 per wave (SIMD-balanced: 2 full passes + 25 lanes)
            #pragma unroll 1
            for (int j = 0; j < 3; ++j) {
                if (j < 2 || lni < 25) {
                    int i = wvi * 153 + j * 64 + lni;
                    int hy = i / 34, hx = i - hy * 34;
                    const float* pb = ca + (2 * hy) * 70 + 2 * hx;
                    v2f pr[4][2];
                    #pragma unroll
                    for (int r = 0; r < 4; ++r) {
                        pr[r][0] = *(const v2f*)(pb + r * 70);
                        pr[r][1] = *(const v2f*)(pb + r * 70 + 2);
                    }
                    bool oob = ((unsigned)(hy0 + hy) >= 128u) | ((unsigned)(hx0 + hx) >= 128u);
                    v2f am[2][4];   // [ocpair][pos: p00 p01 p10 p11]
                    #pragma unroll
                    for (int ky = 0; ky < 3; ++ky)
                    #pragma unroll
                    for (int kx = 0; kx < 3; ++kx) {
                        #pragma unroll
                        for (int o2 = 0; o2 < 2; ++o2)
                        #pragma unroll
                        for (int dy = 0; dy < 2; ++dy)
                        #pragma unroll
                        for (int dx = 0; dx < 2; ++dx) {
                            v2f d = pr[ky + dy][(kx + dx) >> 1];
                            if (ky == 0 && kx == 0) {
                                if (((kx + dx) & 1) == 0) PK_MUL_W0(am[o2][dy * 2 + dx], wp1[o2][0], d);
                                else                      PK_MUL_W1(am[o2][dy * 2 + dx], wp1[o2][0], d);
                            } else {
                                if (((kx + dx) & 1) == 0) PK_FMA_W0(am[o2][dy * 2 + dx], wp1[o2][ky * 3 + kx], d);
                                else                      PK_FMA_W1(am[o2][dy * 2 + dx], wp1[o2][ky * 3 + kx], d);
                            }
                        }
                    }
                    #pragma unroll
                    for (int o2 = 0; o2 < 2; ++o2) {
                        float mx = fmaxf(fmaxf(am[o2][0].x, am[o2][1].x),
                                         fmaxf(am[o2][2].x, am[o2][3].x));
                        float my = fmaxf(fmaxf(am[o2][0].y, am[o2][1].y),
                                         fmaxf(am[o2][2].y, am[o2][3].y));
                        mx = fmaxf(mx + b1[cc * 4 + o2 * 2    ], 0.f);
                        my = fmaxf(my + b1[cc * 4 + o2 * 2 + 1], 0.f);
                        h1s[((o2 * 2    ) * 18 + hy) * 34 + hx] = oob ? 0.f : mx;
                        h1s[((o2 * 2 + 1) * 18 + hy) * 34 + hx] = oob ? 0.f : my;
                    }
                }
            }
            __syncthreads();

            // Phase b: conv2 accumulate over these 4 input channels (4 oc per group)
            #pragma unroll
            for (int icl = 0; icl < 4; ++icl) {
                int ic = cc * 4 + icl;
                // weight pairs hoisted ahead of LDS reads (s_load overlaps ds_read)
                v2f wl[2][9];
                #pragma unroll
                for (int o2 = 0; o2 < 2; ++o2) {
                    int oc0 = ocg * 4 + o2 * 2;
                    #pragma unroll
                    for (int k = 0; k < 9; ++k)
                        wl[o2][k] = (v2f){ w2[((oc0    ) * 16 + ic) * 9 + k],
                                           w2[((oc0 + 1) * 16 + ic) * 9 + k] };
                }
                const float* base = h1s + (icl * 18 + ly * 2) * 34 + lx * 2;
                v2f wr[4][2];
                #pragma unroll
                for (int r = 0; r < 4; ++r) {
                    wr[r][0] = *(const v2f*)(base + r * 34);
                    wr[r][1] = *(const v2f*)(base + r * 34 + 2);
                }
                #pragma unroll
                for (int ky = 0; ky < 3; ++ky)
                #pragma unroll
                for (int kx = 0; kx < 3; ++kx)
                #pragma unroll
                for (int o2 = 0; o2 < 2; ++o2) {
                    #pragma unroll
                    for (int r = 0; r < 2; ++r)
                    #pragma unroll
                    for (int c = 0; c < 2; ++c) {
                        v2f d = wr[r + ky][(c + kx) >> 1];
                        if (((c + kx) & 1) == 0) PK_FMA_W0(acc2[o2][r][c], wl[o2][ky * 3 + kx], d);
                        else                     PK_FMA_W1(acc2[o2][r][c], wl[o2][ky * 3 + kx], d);
                    }
                }
            }
        }

        // Epilogue: bias+relu+pool2 of conv2 (4 oc per thread), exchange via LDS,
        // then conv3 (1x1, 8->4) -> low
        float h2v[4];
        #pragma unroll
        for (int o2 = 0; o2 < 2; ++o2) {
            float mx = fmaxf(fmaxf(acc2[o2][0][0].x, acc2[o2][0][1].x),
                             fmaxf(acc2[o2][1][0].x, acc2[o2][1][1].x));
            float my = fmaxf(fmaxf(acc2[o2][0][0].y, acc2[o2][0][1].y),
                             fmaxf(acc2[o2][1][0].y, acc2[o2][1][1].y));
            h2v[o2 * 2    ] = fmaxf(mx + b2[ocg * 4 + o2 * 2    ], 0.f);
            h2v[o2 * 2 + 1] = fmaxf(my + b2[ocg * 4 + o2 * 2 + 1], 0.f);
        }
        __syncthreads();                 // conv2 done reading h1s; reuse for h2
        float* hx2 = h1s;                // [128 pos][9] stride 9 -> conflict-free
        #pragma unroll
        for (int j = 0; j < 4; ++j) hx2[pos * 9 + ocg * 4 + j] = h2v[j];
        __syncthreads();

        float hv[8];
        #pragma unroll
        for (int ic = 0; ic < 8; ++ic) hv[ic] = hx2[pos * 9 + ic];
        float* dst = outLow + img * 16384;
        int posg = (tyy * 8 + ly) * 64 + txx * 16 + lx;
        #pragma unroll
        for (int jo = 0; jo < 2; ++jo) {
            int oc3 = ocg * 2 + jo;      // this thread writes oc3 {2*ocg, 2*ocg+1}
            float s = b3[oc3];
            #pragma unroll
            for (int ic = 0; ic < 8; ++ic) s += w3[oc3 * 8 + ic] * hv[ic];
            dst[oc3 * 4096 + posg] = s;
        }
    }
}

extern "C" void kernel_launch(void* const* d_in, const int* in_sizes, int n_in,
                              void* d_out, int out_size, void* d_ws, size_t ws_size,
                              hipStream_t stream) {
    const float* x  = (const float*)d_in[0];
    const float* w1 = (const float*)d_in[1];
    const float* b1 = (const float*)d_in[2];
    const float* w2 = (const float*)d_in[3];
    const float* b2 = (const float*)d_in[4];
    const float* w3 = (const float*)d_in[5];
    const float* b3 = (const float*)d_in[6];
    float* out     = (float*)d_out;
    float* outLow  = out;                 // 1,572,864 floats
    float* outHigh = out + 1572864;       // 12,582,912 floats

    fused_all_kernel<<<1536, 256, 0, stream>>>(x, w1, b1, w2, b2, w3, b3,
                                               outLow, outHigh);
}

// Round 8
// 224.739 us; speedup vs baseline: 1.0296x; 1.0090x over previous
//
#include <hip/hip_runtime.h>

// Problem: B=32, C=3, H=512, W=512 -> NIMG = 96 flat images
// R8 = resubmit of R7 (round-7 bench was an infra failure: container died
//   before compile/run, same signature as round 3 which passed on resubmit;
//   source re-audited: no deadlock, no OOB, no LDS hazard).
// R7 structure: grid 2048 = 256 CU x 8 resident blocks, ONE full round, zero
//   tail, uniform per-block work = 1.5 tiles:
//   - FULL 8x16-pooled tile (images 0..63: 2048 tiles, R2 geometry/body)
//   - HALF 4x16-pooled tile (images 64..95: 1024 tiles, each split across 2
//     blocks; R5 geometry/body)
//   Concurrency 8-deep the whole dispatch (issue-util ~0.8 measured at 8-deep)
//   AND perfect packing AND minimal busy-time.
// R1: conv1/conv2 use v_pk_fma_f32 (packed fp32) over oc pairs (SGPR weights,
//   free activation broadcast via op_sel). R2: 8x16 tile geometry. R4: LDS
//   20,480 B (stride 70/34). R7: UNBALANCED task loops restored (R2 style) —
//   execz-skip is cheaper than balanced-with-mask (R4/R6 busy-time +12%).
// Numerics bit-identical to R2/R4.

typedef float v2f __attribute__((ext_vector_type(2)));

// acc(pair over oc) += w(pair over oc, SGPR) * broadcast(data.word0)
#define PK_FMA_W0(acc, w, d) \
    asm("v_pk_fma_f32 %0, %1, %2, %0 op_sel:[0,0,0] op_sel_hi:[1,0,1]" \
        : "+v"(acc) : "s"(w), "v"(d))
// acc += w * broadcast(data.word1)
#define PK_FMA_W1(acc, w, d) \
    asm("v_pk_fma_f32 %0, %1, %2, %0 op_sel:[0,1,0] op_sel_hi:[1,1,1]" \
        : "+v"(acc) : "s"(w), "v"(d))
// dst = w * broadcast(data.word0)   (accumulator init without v_mov zeroing)
#define PK_MUL_W0(dst, w, d) \
    asm("v_pk_mul_f32 %0, %1, %2 op_sel:[0,0] op_sel_hi:[1,0]" \
        : "=v"(dst) : "s"(w), "v"(d))
#define PK_MUL_W1(dst, w, d) \
    asm("v_pk_mul_f32 %0, %1, %2 op_sel:[0,1] op_sel_hi:[1,1]" \
        : "=v"(dst) : "s"(w), "v"(d))

__global__ __launch_bounds__(256, 8) void fused_all_kernel(
    const float* __restrict__ x,
    const float* __restrict__ w1, const float* __restrict__ b1,
    const float* __restrict__ w2, const float* __restrict__ b2,
    const float* __restrict__ w3, const float* __restrict__ b3,
    float* __restrict__ outLow, float* __restrict__ outHigh)
{
    __shared__ __align__(16) float ca[38 * 70];      // cA tile, rows stride 70
    __shared__ __align__(16) float h1s[4 * 18 * 34]; // conv1 chunk (reused for h2 xchg)

    int tid = threadIdx.x;

    // ==================== PART 1: FULL 8x16 TILE (img 0..63) ====================
    {
        int tIdx = blockIdx.x;                 // 0..2047
        int img  = tIdx >> 5;
        int t    = tIdx & 31;
        int tyy = t >> 2, txx = t & 3;         // 8 pooled rows x 16 cols
        int hy0 = tyy * 16 - 1, hx0 = txx * 32 - 1; // h1 tile origin (18x34 incl halo)
        int cy0 = tyy * 32 - 3, cx0 = txx * 64 - 3; // cA tile origin (38x70)

        const float* xi = x + img * 262144;
        float* hb = outHigh + img * 131072;

        // ---- Phase 0a: interior 32x64 cA (coalesced), cH/cV -> global ----
        #pragma unroll
        for (int k = 0; k < 2; ++k) {
            int i = tid + k * 256;
            int row = i >> 4, cg = i & 15;
            int gy = tyy * 32 + row;
            int gx = txx * 64 + cg * 4;
            const float* r0 = xi + (2 * gy) * 512 + 2 * gx;
            const float* r1 = r0 + 512;
            float4 t0 = *(const float4*)(r0);
            float4 t1 = *(const float4*)(r0 + 4);
            float4 u0 = *(const float4*)(r1);
            float4 u1 = *(const float4*)(r1 + 4);
            float4 vA, vH, vV;
            vA.x = (t0.x + t0.y + u0.x + u0.y) * 0.5f;
            vH.x = (t0.x + t0.y - u0.x - u0.y) * 0.5f;
            vV.x = (t0.x - t0.y + u0.x - u0.y) * 0.5f;
            vA.y = (t0.z + t0.w + u0.z + u0.w) * 0.5f;
            vH.y = (t0.z + t0.w - u0.z - u0.w) * 0.5f;
            vV.y = (t0.z - t0.w + u0.z - u0.w) * 0.5f;
            vA.z = (t1.x + t1.y + u1.x + u1.y) * 0.5f;
            vH.z = (t1.x + t1.y - u1.x - u1.y) * 0.5f;
            vV.z = (t1.x - t1.y + u1.x - u1.y) * 0.5f;
            vA.w = (t1.z + t1.w + u1.z + u1.w) * 0.5f;
            vH.w = (t1.z + t1.w - u1.z - u1.w) * 0.5f;
            vV.w = (t1.z - t1.w + u1.z - u1.w) * 0.5f;
            int po = (gy << 8) + gx;
            *(float4*)(hb + po) = vH;
            *(float4*)(hb + 65536 + po) = vV;
            float* cp = ca + (row + 3) * 70 + cg * 4 + 3;
            cp[0] = vA.x; cp[1] = vA.y; cp[2] = vA.z; cp[3] = vA.w;
        }

        // ---- Phase 0b: 3-wide halo ring of cA (612 points), vA only ----
        #pragma unroll 1
        for (int i = tid; i < 612; i += 256) {
            int r, c;
            if (i < 210)      { r = i / 70;              c = i - r * 70; }
            else if (i < 420) { int j = i - 210; r = 35 + j / 70; c = j - (j / 70) * 70; }
            else              { int j = i - 420; r = 3 + j / 6; int k6 = j - (j / 6) * 6;
                                c = (k6 < 3) ? k6 : (64 + k6); }   // {0,1,2,67,68,69}
            int gy = cy0 + r, gx = cx0 + c;
            float v = 0.f;
            if ((unsigned)gy < 256u && (unsigned)gx < 256u) {
                const float* p0 = xi + (2 * gy) * 512 + 2 * gx;
                float2 a = *(const float2*)(p0);
                float2 b = *(const float2*)(p0 + 512);
                v = (a.x + a.y + b.x + b.y) * 0.5f;
            }
            ca[r * 70 + c] = v;
        }

        int pos = tid & 127;
        int ocg = __builtin_amdgcn_readfirstlane(tid >> 7);
        int ly = pos >> 4, lx = pos & 15;

        v2f acc2[2][2][2];
        #pragma unroll
        for (int o2 = 0; o2 < 2; ++o2)
            #pragma unroll
            for (int r = 0; r < 2; ++r)
                #pragma unroll
                for (int c = 0; c < 2; ++c) acc2[o2][r][c] = (v2f){0.f, 0.f};

        __syncthreads();

        #pragma unroll 1
        for (int cc = 0; cc < 4; ++cc) {
            v2f wp1[2][9];
            #pragma unroll
            for (int o2 = 0; o2 < 2; ++o2)
                #pragma unroll
                for (int k = 0; k < 9; ++k)
                    wp1[o2][k] = (v2f){ w1[(cc * 4 + o2 * 2    ) * 9 + k],
                                        w1[(cc * 4 + o2 * 2 + 1) * 9 + k] };
            if (cc) __syncthreads();

            // Phase a: h1 chunk = pool2(relu(conv1)), 4 oc, 18x34 (incl halo)
            #pragma unroll 1
            for (int i = tid; i < 612; i += 256) {
                int hy = i / 34, hx = i - hy * 34;
                const float* pb = ca + (2 * hy) * 70 + 2 * hx;
                v2f pr[4][2];
                #pragma unroll
                for (int r = 0; r < 4; ++r) {
                    pr[r][0] = *(const v2f*)(pb + r * 70);
                    pr[r][1] = *(const v2f*)(pb + r * 70 + 2);
                }
                bool oob = ((unsigned)(hy0 + hy) >= 128u) | ((unsigned)(hx0 + hx) >= 128u);
                v2f am[2][4];
                #pragma unroll
                for (int ky = 0; ky < 3; ++ky)
                #pragma unroll
                for (int kx = 0; kx < 3; ++kx) {
                    #pragma unroll
                    for (int o2 = 0; o2 < 2; ++o2)
                    #pragma unroll
                    for (int dy = 0; dy < 2; ++dy)
                    #pragma unroll
                    for (int dx = 0; dx < 2; ++dx) {
                        v2f d = pr[ky + dy][(kx + dx) >> 1];
                        if (ky == 0 && kx == 0) {
                            if (((kx + dx) & 1) == 0) PK_MUL_W0(am[o2][dy * 2 + dx], wp1[o2][0], d);
                            else                      PK_MUL_W1(am[o2][dy * 2 + dx], wp1[o2][0], d);
                        } else {
                            if (((kx + dx) & 1) == 0) PK_FMA_W0(am[o2][dy * 2 + dx], wp1[o2][ky * 3 + kx], d);
                            else                      PK_FMA_W1(am[o2][dy * 2 + dx], wp1[o2][ky * 3 + kx], d);
                        }
                    }
                }
                #pragma unroll
                for (int o2 = 0; o2 < 2; ++o2) {
                    float mx = fmaxf(fmaxf(am[o2][0].x, am[o2][1].x),
                                     fmaxf(am[o2][2].x, am[o2][3].x));
                    float my = fmaxf(fmaxf(am[o2][0].y, am[o2][1].y),
                                     fmaxf(am[o2][2].y, am[o2][3].y));
                    mx = fmaxf(mx + b1[cc * 4 + o2 * 2    ], 0.f);
                    my = fmaxf(my + b1[cc * 4 + o2 * 2 + 1], 0.f);
                    h1s[((o2 * 2    ) * 18 + hy) * 34 + hx] = oob ? 0.f : mx;
                    h1s[((o2 * 2 + 1) * 18 + hy) * 34 + hx] = oob ? 0.f : my;
                }
            }
            __syncthreads();

            // Phase b: conv2 accumulate over these 4 input channels (4 oc/group)
            #pragma unroll
            for (int icl = 0; icl < 4; ++icl) {
                int ic = cc * 4 + icl;
                v2f wl[2][9];
                #pragma unroll
                for (int o2 = 0; o2 < 2; ++o2) {
                    int oc0 = ocg * 4 + o2 * 2;
                    #pragma unroll
                    for (int k = 0; k < 9; ++k)
                        wl[o2][k] = (v2f){ w2[((oc0    ) * 16 + ic) * 9 + k],
                                           w2[((oc0 + 1) * 16 + ic) * 9 + k] };
                }
                const float* base = h1s + (icl * 18 + ly * 2) * 34 + lx * 2;
                v2f wr[4][2];
                #pragma unroll
                for (int r = 0; r < 4; ++r) {
                    wr[r][0] = *(const v2f*)(base + r * 34);
                    wr[r][1] = *(const v2f*)(base + r * 34 + 2);
                }
                #pragma unroll
                for (int ky = 0; ky < 3; ++ky)
                #pragma unroll
                for (int kx = 0; kx < 3; ++kx)
                #pragma unroll
                for (int o2 = 0; o2 < 2; ++o2) {
                    #pragma unroll
                    for (int r = 0; r < 2; ++r)
                    #pragma unroll
                    for (int c = 0; c < 2; ++c) {
                        v2f d = wr[r + ky][(c + kx) >> 1];
                        if (((c + kx) & 1) == 0) PK_FMA_W0(acc2[o2][r][c], wl[o2][ky * 3 + kx], d);
                        else                     PK_FMA_W1(acc2[o2][r][c], wl[o2][ky * 3 + kx], d);
                    }
                }
            }
        }

        // Epilogue: bias+relu+pool2 of conv2, LDS exchange, conv3 -> low
        float h2v[4];
        #pragma unroll
        for (int o2 = 0; o2 < 2; ++o2) {
            float mx = fmaxf(fmaxf(acc2[o2][0][0].x, acc2[o2][0][1].x),
                             fmaxf(acc2[o2][1][0].x, acc2[o2][1][1].x));
            float my = fmaxf(fmaxf(acc2[o2][0][0].y, acc2[o2][0][1].y),
                             fmaxf(acc2[o2][1][0].y, acc2[o2][1][1].y));
            h2v[o2 * 2    ] = fmaxf(mx + b2[ocg * 4 + o2 * 2    ], 0.f);
            h2v[o2 * 2 + 1] = fmaxf(my + b2[ocg * 4 + o2 * 2 + 1], 0.f);
        }
        __syncthreads();                 // conv2 done reading h1s; reuse for h2
        float* hx2 = h1s;                // [128 pos][9] stride 9 -> conflict-free
        #pragma unroll
        for (int j = 0; j < 4; ++j) hx2[pos * 9 + ocg * 4 + j] = h2v[j];
        __syncthreads();

        float hv[8];
        #pragma unroll
        for (int ic = 0; ic < 8; ++ic) hv[ic] = hx2[pos * 9 + ic];
        float* dst = outLow + img * 16384;
        int posg = (tyy * 8 + ly) * 64 + txx * 16 + lx;
        #pragma unroll
        for (int jo = 0; jo < 2; ++jo) {
            int oc3 = ocg * 2 + jo;
            float s = b3[oc3];
            #pragma unroll
            for (int ic = 0; ic < 8; ++ic) s += w3[oc3 * 8 + ic] * hv[ic];
            dst[oc3 * 4096 + posg] = s;
        }
    }

    // ==================== PART 2: HALF 4x16 TILE (img 64..95) ====================
    // Tile t2 = 2048 + (blockIdx.x>>1); row-half h = blockIdx.x&1.
    // NOTE: half's first __syncthreads (post-ca) orders Part-1's hx2 reads
    //       before half's h1s writes; ca writes don't conflict (full's last ca
    //       read precedes full's pre-h2 barrier for all threads).
    {
        int b  = blockIdx.x;
        int t2 = 2048 + (b >> 1);              // 2048..3071
        int img = t2 >> 5;                     // 64..95
        int t   = t2 & 31;
        int rs = ((t >> 2) << 1) + (b & 1);    // 4-row strip 0..15
        int cs = t & 3;
        int hy0 = rs * 8 - 1, hx0 = cs * 32 - 1;  // h1 origin (10x34 incl halo)
        int cy0 = rs * 16 - 3, cx0 = cs * 64 - 3; // cA origin (22x70)

        const float* xi = x + img * 262144;
        float* hb = outHigh + img * 131072;

        // ---- Phase 0a: interior 16x64 cA, cH/cV -> global (256 tasks) ----
        {
            int i = tid;
            int row = i >> 4, cg = i & 15;
            int gy = rs * 16 + row;
            int gx = cs * 64 + cg * 4;
            const float* r0 = xi + (2 * gy) * 512 + 2 * gx;
            const float* r1 = r0 + 512;
            float4 t0 = *(const float4*)(r0);
            float4 t1 = *(const float4*)(r0 + 4);
            float4 u0 = *(const float4*)(r1);
            float4 u1 = *(const float4*)(r1 + 4);
            float4 vA, vH, vV;
            vA.x = (t0.x + t0.y + u0.x + u0.y) * 0.5f;
            vH.x = (t0.x + t0.y - u0.x - u0.y) * 0.5f;
            vV.x = (t0.x - t0.y + u0.x - u0.y) * 0.5f;
            vA.y = (t0.z + t0.w + u0.z + u0.w) * 0.5f;
            vH.y = (t0.z + t0.w - u0.z - u0.w) * 0.5f;
            vV.y = (t0.z - t0.w + u0.z - u0.w) * 0.5f;
            vA.z = (t1.x + t1.y + u1.x + u1.y) * 0.5f;
            vH.z = (t1.x + t1.y - u1.x - u1.y) * 0.5f;
            vV.z = (t1.x - t1.y + u1.x - u1.y) * 0.5f;
            vA.w = (t1.z + t1.w + u1.z + u1.w) * 0.5f;
            vH.w = (t1.z + t1.w - u1.z - u1.w) * 0.5f;
            vV.w = (t1.z - t1.w + u1.z - u1.w) * 0.5f;
            int po = (gy << 8) + gx;
            *(float4*)(hb + po) = vH;
            *(float4*)(hb + 65536 + po) = vV;
            float* cp = ca + (row + 3) * 70 + cg * 4 + 3;
            cp[0] = vA.x; cp[1] = vA.y; cp[2] = vA.z; cp[3] = vA.w;
        }

        // ---- Phase 0b: halo ring (516 points) ----
        // rows {0,1,2}+{19,20,21} full width 70, rows 3..18 cols {0,1,2,67,68,69}
        #pragma unroll 1
        for (int i = tid; i < 516; i += 256) {
            int r, c;
            if (i < 210)      { r = i / 70;              c = i - r * 70; }
            else if (i < 420) { int j = i - 210; r = 19 + j / 70; c = j - (j / 70) * 70; }
            else              { int j = i - 420; r = 3 + j / 6; int k6 = j - (j / 6) * 6;
                                c = (k6 < 3) ? k6 : (64 + k6); }
            int gy = cy0 + r, gx = cx0 + c;
            float v = 0.f;
            if ((unsigned)gy < 256u && (unsigned)gx < 256u) {
                const float* p0 = xi + (2 * gy) * 512 + 2 * gx;
                float2 a = *(const float2*)(p0);
                float2 b2v = *(const float2*)(p0 + 512);
                v = (a.x + a.y + b2v.x + b2v.y) * 0.5f;
            }
            ca[r * 70 + c] = v;
        }

        int pos = tid & 63;
        int ocg = __builtin_amdgcn_readfirstlane(tid >> 6);  // wave id, 2 oc
        int ly = pos >> 4, lx = pos & 15;

        v2f acc2[2][2];
        #pragma unroll
        for (int r = 0; r < 2; ++r)
            #pragma unroll
            for (int c = 0; c < 2; ++c) acc2[r][c] = (v2f){0.f, 0.f};

        __syncthreads();   // ca ready; also orders Part-1 hx2 reads vs h1s writes

        #pragma unroll 1
        for (int cc = 0; cc < 4; ++cc) {
            v2f wp1[2][9];
            #pragma unroll
            for (int o2 = 0; o2 < 2; ++o2)
                #pragma unroll
                for (int k = 0; k < 9; ++k)
                    wp1[o2][k] = (v2f){ w1[(cc * 4 + o2 * 2    ) * 9 + k],
                                        w1[(cc * 4 + o2 * 2 + 1) * 9 + k] };
            if (cc) __syncthreads();

            // Phase a: h1 chunk, 4 oc, 10x34 (incl halo): 340 tasks
            #pragma unroll 1
            for (int i = tid; i < 340; i += 256) {
                int hy = i / 34, hx = i - hy * 34;
                const float* pb = ca + (2 * hy) * 70 + 2 * hx;
                v2f pr[4][2];
                #pragma unroll
                for (int r = 0; r < 4; ++r) {
                    pr[r][0] = *(const v2f*)(pb + r * 70);
                    pr[r][1] = *(const v2f*)(pb + r * 70 + 2);
                }
                bool oob = ((unsigned)(hy0 + hy) >= 128u) | ((unsigned)(hx0 + hx) >= 128u);
                v2f am[2][4];
                #pragma unroll
                for (int ky = 0; ky < 3; ++ky)
                #pragma unroll
                for (int kx = 0; kx < 3; ++kx) {
                    #pragma unroll
                    for (int o2 = 0; o2 < 2; ++o2)
                    #pragma unroll
                    for (int dy = 0; dy < 2; ++dy)
                    #pragma unroll
                    for (int dx = 0; dx < 2; ++dx) {
                        v2f d = pr[ky + dy][(kx + dx) >> 1];
                        if (ky == 0 && kx == 0) {
                            if (((kx + dx) & 1) == 0) PK_MUL_W0(am[o2][dy * 2 + dx], wp1[o2][0], d);
                            else                      PK_MUL_W1(am[o2][dy * 2 + dx], wp1[o2][0], d);
                        } else {
                            if (((kx + dx) & 1) == 0) PK_FMA_W0(am[o2][dy * 2 + dx], wp1[o2][ky * 3 + kx], d);
                            else                      PK_FMA_W1(am[o2][dy * 2 + dx], wp1[o2][ky * 3 + kx], d);
                        }
                    }
                }
                #pragma unroll
                for (int o2 = 0; o2 < 2; ++o2) {
                    float mx = fmaxf(fmaxf(am[o2][0].x, am[o2][1].x),
                                     fmaxf(am[o2][2].x, am[o2][3].x));
                    float my = fmaxf(fmaxf(am[o2][0].y, am[o2][1].y),
                                     fmaxf(am[o2][2].y, am[o2][3].y));
                    mx = fmaxf(mx + b1[cc * 4 + o2 * 2    ], 0.f);
                    my = fmaxf(my + b1[cc * 4 + o2 * 2 + 1], 0.f);
                    h1s[((o2 * 2    ) * 10 + hy) * 34 + hx] = oob ? 0.f : mx;
                    h1s[((o2 * 2 + 1) * 10 + hy) * 34 + hx] = oob ? 0.f : my;
                }
            }
            __syncthreads();

            // Phase b: conv2 accumulate (2 oc for this wave)
            #pragma unroll
            for (int icl = 0; icl < 4; ++icl) {
                int ic = cc * 4 + icl;
                v2f wl[9];
                {
                    int oc0 = ocg * 2;
                    #pragma unroll
                    for (int k = 0; k < 9; ++k)
                        wl[k] = (v2f){ w2[((oc0    ) * 16 + ic) * 9 + k],
                                       w2[((oc0 + 1) * 16 + ic) * 9 + k] };
                }
                const float* base = h1s + (icl * 10 + ly * 2) * 34 + lx * 2;
                v2f wr[4][2];
                #pragma unroll
                for (int r = 0; r < 4; ++r) {
                    wr[r][0] = *(const v2f*)(base + r * 34);
                    wr[r][1] = *(const v2f*)(base + r * 34 + 2);
                }
                #pragma unroll
                for (int ky = 0; ky < 3; ++ky)
                #pragma unroll
                for (int kx = 0; kx < 3; ++kx) {
                    #pragma unroll
                    for (int r = 0; r < 2; ++r)
                    #pragma unroll
                    for (int c = 0; c < 2; ++c) {
                        v2f d = wr[r + ky][(c + kx) >> 1];
                        if (((c + kx) & 1) == 0) PK_FMA_W0(acc2[r][c], wl[ky * 3 + kx], d);
                        else                     PK_FMA_W1(acc2[r][c], wl[ky * 3 + kx], d);
                    }
                }
            }
        }

        // Epilogue: bias+relu+pool2 (2 oc/thread), LDS exchange, conv3 -> low
        float h2a, h2b;
        {
            float mx = fmaxf(fmaxf(acc2[0][0].x, acc2[0][1].x),
                             fmaxf(acc2[1][0].x, acc2[1][1].x));
            float my = fmaxf(fmaxf(acc2[0][0].y, acc2[0][1].y),
                             fmaxf(acc2[1][0].y, acc2[1][1].y));
            h2a = fmaxf(mx + b2[ocg * 2    ], 0.f);
            h2b = fmaxf(my + b2[ocg * 2 + 1], 0.f);
        }
        __syncthreads();                 // conv2 done reading h1s; reuse for h2
        float* hx2 = h1s;                // [64 pos][9] stride 9 -> conflict-free
        hx2[pos * 9 + ocg * 2    ] = h2a;
        hx2[pos * 9 + ocg * 2 + 1] = h2b;
        __syncthreads();

        float hv[8];
        #pragma unroll
        for (int ic = 0; ic < 8; ++ic) hv[ic] = hx2[pos * 9 + ic];
        float* dst = outLow + img * 16384;
        int posg = (rs * 4 + ly) * 64 + cs * 16 + lx;
        int oc3 = ocg;                   // one conv3 output per thread
        float sacc = b3[oc3];
        #pragma unroll
        for (int ic = 0; ic < 8; ++ic) sacc += w3[oc3 * 8 + ic] * hv[ic];
        dst[oc3 * 4096 + posg] = sacc;
    }
}

extern "C" void kernel_launch(void* const* d_in, const int* in_sizes, int n_in,
                              void* d_out, int out_size, void* d_ws, size_t ws_size,
                              hipStream_t stream) {
    const float* x  = (const float*)d_in[0];
    const float* w1 = (const float*)d_in[1];
    const float* b1 = (const float*)d_in[2];
    const float* w2 = (const float*)d_in[3];
    const float* b2 = (const float*)d_in[4];
    const float* w3 = (const float*)d_in[5];
    const float* b3 = (const float*)d_in[6];
    float* out     = (float*)d_out;
    float* outLow  = out;                 // 1,572,864 floats
    float* outHigh = out + 1572864;       // 12,582,912 floats

    fused_all_kernel<<<2048, 256, 0, stream>>>(x, w1, b1, w2, b2, w3, b3,
                                               outLow, outHigh);
}